// Round 5
// baseline (311.051 us; speedup 1.0000x reference)
//
#include <hip/hip_runtime.h>
#include <math.h>

#define IMG_H 768
#define IMG_W 768
#define BATCH 16
#define TH 4                       // output rows per block
#define TPB 192                    // 768/4 px per thread-row (3 waves)
#define NSTRIPS (IMG_H / TH)       // 192
#define NBLOCKS (NSTRIPS * BATCH)  // 3072
#define NPIX ((size_t)BATCH * IMG_H * IMG_W)  // 9437184

struct Raw  { float4 m; float ev; };   // aligned quad + edge value (lane 0 / 63 only)
struct Row6 { float v[6]; };           // x0-1 .. x0+4

__device__ __forceinline__ Raw issue_load(const float* __restrict__ img, int row, int x0, int lane) {
    Raw r;
    r.m = make_float4(0.f, 0.f, 0.f, 0.f);
    r.ev = 0.f;
    if (row >= 0 && row < IMG_H) {
        const float* p = img + row * IMG_W + x0;
        r.m = *(const float4*)p;       // 16B aligned
        bool e0 = (lane == 0), e63 = (lane == 63);
        if (e0 | e63) {                // one masked VMEM, 2 active lanes/wave
            int off  = e0 ? -1 : 4;
            bool inb = e0 ? (x0 > 0) : (x0 + 4 < IMG_W);
            if (inb) r.ev = p[off];
        }
    }
    return r;
}

// x-halo from neighbor lanes (wave covers a contiguous 256-px span)
__device__ __forceinline__ Row6 expand(const Raw& r, int lane) {
    Row6 o;
    float left  = __shfl_up(r.m.w, 1);
    float right = __shfl_down(r.m.x, 1);
    if (lane == 0)  left  = r.ev;
    if (lane == 63) right = r.ev;
    o.v[0] = left; o.v[1] = r.m.x; o.v[2] = r.m.y; o.v[3] = r.m.z; o.v[4] = r.m.w; o.v[5] = right;
    return o;
}

__device__ __forceinline__ float sob(const Row6& r0, const Row6& r1, const Row6& r2, int j) {
    float gx = (r0.v[j + 2] - r0.v[j]) + 2.f * (r1.v[j + 2] - r1.v[j]) + (r2.v[j + 2] - r2.v[j]);
    float gy = (r0.v[j] - r2.v[j]) + 2.f * (r0.v[j + 1] - r2.v[j + 1]) + (r0.v[j + 2] - r2.v[j + 2]);
    return fabsf(gx) + fabsf(gy);
}

__global__ __launch_bounds__(TPB, 4) void sobel_loss_main(
    const float* __restrict__ vis, const float* __restrict__ ir,
    const float* __restrict__ X, const float* __restrict__ Y,
    float* __restrict__ part)   // part: [3][NBLOCKS]
{
    __shared__ float red[3][3];

    const int tid  = threadIdx.x;
    const int lane = tid & 63;
    const int x0   = tid * 4;
    const int y0   = blockIdx.x * TH;
    const size_t base = (size_t)blockIdx.y * (IMG_H * IMG_W);
    const int bid = blockIdx.y * NSTRIPS + blockIdx.x;

    const float* i0 = vis + base;
    const float* i1 = ir + base;
    const float* i2 = X + base;
    const float* i3 = Y + base;

    // ---- prologue: rows y0-1, y0, y0+1 for all 4 images (12 loads in flight) ----
    Raw ta0 = issue_load(i0, y0 - 1, x0, lane), ta1 = issue_load(i0, y0, x0, lane), ta2 = issue_load(i0, y0 + 1, x0, lane);
    Raw tb0 = issue_load(i1, y0 - 1, x0, lane), tb1 = issue_load(i1, y0, x0, lane), tb2 = issue_load(i1, y0 + 1, x0, lane);
    Raw tc0 = issue_load(i2, y0 - 1, x0, lane), tc1 = issue_load(i2, y0, x0, lane), tc2 = issue_load(i2, y0 + 1, x0, lane);
    Raw td0 = issue_load(i3, y0 - 1, x0, lane), td1 = issue_load(i3, y0, x0, lane), td2 = issue_load(i3, y0 + 1, x0, lane);

    Row6 a0 = expand(ta0, lane), a1 = expand(ta1, lane), a2 = expand(ta2, lane);
    Row6 b0 = expand(tb0, lane), b1 = expand(tb1, lane), b2 = expand(tb2, lane);
    Row6 c0 = expand(tc0, lane), c1 = expand(tc1, lane), c2 = expand(tc2, lane);
    Row6 d0 = expand(td0, lane), d1 = expand(td1, lane), d2 = expand(td2, lane);

    // row y0+2 in flight
    Raw an = issue_load(i0, y0 + 2, x0, lane);
    Raw bn = issue_load(i1, y0 + 2, x0, lane);
    Raw cn = issue_load(i2, y0 + 2, x0, lane);
    Raw dn = issue_load(i3, y0 + 2, x0, lane);

    float sX2 = 0.f, sY2 = 0.f, sL1 = 0.f;

    #pragma unroll 1
    for (int k = 0; k < TH; ++k) {
        const bool more = (k < TH - 1);
        Raw an2, bn2, cn2, dn2;
        if (more) {    // issue row y0+k+3 BEFORE compute: >=1 compute phase in flight
            an2 = issue_load(i0, y0 + k + 3, x0, lane);
            bn2 = issue_load(i1, y0 + k + 3, x0, lane);
            cn2 = issue_load(i2, y0 + k + 3, x0, lane);
            dn2 = issue_load(i3, y0 + k + 3, x0, lane);
        }

        #pragma unroll
        for (int j = 0; j < 4; ++j) {
            float gv = sob(a0, a1, a2, j);
            float gi = sob(b0, b1, b2, j);
            float gX = sob(c0, c1, c2, j);
            float gY = sob(d0, d1, d2, j);
            sX2 += gX * gX;
            sY2 += gY * gY;
            sL1 += fabsf(gX - fmaxf(gv, gi));
        }

        if (more) {
            a0 = a1; a1 = a2; a2 = expand(an, lane); an = an2;
            b0 = b1; b1 = b2; b2 = expand(bn, lane); bn = bn2;
            c0 = c1; c1 = c2; c2 = expand(cn, lane); cn = cn2;
            d0 = d1; d1 = d2; d2 = expand(dn, lane); dn = dn2;
        }
    }

    #pragma unroll
    for (int off = 32; off > 0; off >>= 1) {
        sX2 += __shfl_down(sX2, off);
        sY2 += __shfl_down(sY2, off);
        sL1 += __shfl_down(sL1, off);
    }
    const int wave = tid >> 6;
    if ((tid & 63) == 0) { red[0][wave] = sX2; red[1][wave] = sY2; red[2][wave] = sL1; }
    __syncthreads();
    if (tid == 0) {
        part[0 * NBLOCKS + bid] = red[0][0] + red[0][1] + red[0][2];
        part[1 * NBLOCKS + bid] = red[1][0] + red[1][1] + red[1][2];
        part[2 * NBLOCKS + bid] = red[2][0] + red[2][1] + red[2][2];
    }
}

__global__ __launch_bounds__(1024) void reduce_finalize(
    const float* __restrict__ part, float* __restrict__ out)
{
    __shared__ float red[3][16];
    const int tid = threadIdx.x;

    float a = 0.f, b = 0.f, c = 0.f;
    for (int i = tid; i < NBLOCKS; i += 1024) {
        a += part[0 * NBLOCKS + i];
        b += part[1 * NBLOCKS + i];
        c += part[2 * NBLOCKS + i];
    }
    #pragma unroll
    for (int off = 32; off > 0; off >>= 1) {
        a += __shfl_down(a, off);
        b += __shfl_down(b, off);
        c += __shfl_down(c, off);
    }
    const int wave = tid >> 6;
    const int lane = tid & 63;
    if (lane == 0) { red[0][wave] = a; red[1][wave] = b; red[2][wave] = c; }
    __syncthreads();
    if (tid == 0) {
        float sa = 0.f, sb = 0.f, sc = 0.f;
        #pragma unroll
        for (int w = 0; w < 16; ++w) { sa += red[0][w]; sb += red[1][w]; sc += red[2][w]; }
        out[0] = sb / sa;                      // loss_in = sumY2 / sumX2
        out[1] = sc * (1.f / (float)NPIX);     // loss_grad = sumL1 / N
    }
}

extern "C" void kernel_launch(void* const* d_in, const int* in_sizes, int n_in,
                              void* d_out, int out_size, void* d_ws, size_t ws_size,
                              hipStream_t stream) {
    const float* vis = (const float*)d_in[0];
    const float* ir  = (const float*)d_in[1];
    const float* X   = (const float*)d_in[2];
    const float* Y   = (const float*)d_in[3];
    float* out = (float*)d_out;
    float* part = (float*)d_ws;   // 3 * NBLOCKS floats = 36 KB

    dim3 grid(NSTRIPS, BATCH);    // 192 x 16 = 3072 blocks
    sobel_loss_main<<<grid, TPB, 0, stream>>>(vis, ir, X, Y, part);
    reduce_finalize<<<1, 1024, 0, stream>>>(part, out);
}

// Round 6
// 51.772 us; speedup vs baseline: 6.0081x; 6.0081x over previous
//
#include <hip/hip_runtime.h>
#include <math.h>

#define IMG_H 768
#define IMG_W 768
#define BATCH 16
#define TH 6                       // output rows per block
#define TPB 192                    // threads per block = 768/4 (3 waves)
#define NSTRIPS (IMG_H / TH)       // 128
#define NBLOCKS (NSTRIPS * BATCH)  // 2048
#define NPIX ((size_t)BATCH * IMG_H * IMG_W)  // 9437184

struct Row6 { float v[6]; };       // x0-1 .. x0+4

__device__ __forceinline__ Row6 load_row(const float* __restrict__ img, int row, int x0) {
    Row6 r;
    if (row < 0 || row >= IMG_H) {           // wave-uniform branch
        #pragma unroll
        for (int i = 0; i < 6; ++i) r.v[i] = 0.f;
        return r;
    }
    const float* p = img + row * IMG_W + x0;
    float4 m = *(const float4*)p;            // 16B-aligned (x0 % 4 == 0)
    r.v[0] = (x0 > 0) ? p[-1] : 0.f;
    r.v[1] = m.x; r.v[2] = m.y; r.v[3] = m.z; r.v[4] = m.w;
    r.v[5] = (x0 + 4 < IMG_W) ? p[4] : 0.f;
    return r;
}

// sobel |gx|+|gy| at output offset j (0..3) from 3 register rows
__device__ __forceinline__ float sob(const Row6& r0, const Row6& r1, const Row6& r2, int j) {
    float gx = (r0.v[j + 2] - r0.v[j]) + 2.f * (r1.v[j + 2] - r1.v[j]) + (r2.v[j + 2] - r2.v[j]);
    float gy = (r0.v[j] - r2.v[j]) + 2.f * (r0.v[j + 1] - r2.v[j + 1]) + (r0.v[j + 2] - r2.v[j + 2]);
    return fabsf(gx) + fabsf(gy);
}

__global__ __launch_bounds__(TPB) void sobel_loss_main(
    const float* __restrict__ vis, const float* __restrict__ ir,
    const float* __restrict__ X, const float* __restrict__ Y,
    float* __restrict__ part)   // part: [3][NBLOCKS]
{
    __shared__ float red[3][3];

    const int tid = threadIdx.x;
    const int x0 = tid * 4;
    const int y0 = blockIdx.x * TH;
    const size_t base = (size_t)blockIdx.y * (IMG_H * IMG_W);
    const int bid = blockIdx.y * NSTRIPS + blockIdx.x;

    const float* i0 = vis + base;
    const float* i1 = ir + base;
    const float* i2 = X + base;
    const float* i3 = Y + base;

    // pipeline: rows k-1, k in place; row k+1 prefetched into an..dn
    Row6 a0 = load_row(i0, y0 - 1, x0), a1 = load_row(i0, y0, x0);
    Row6 b0 = load_row(i1, y0 - 1, x0), b1 = load_row(i1, y0, x0);
    Row6 c0 = load_row(i2, y0 - 1, x0), c1 = load_row(i2, y0, x0);
    Row6 d0 = load_row(i3, y0 - 1, x0), d1 = load_row(i3, y0, x0);

    Row6 an = load_row(i0, y0 + 1, x0);
    Row6 bn = load_row(i1, y0 + 1, x0);
    Row6 cn = load_row(i2, y0 + 1, x0);
    Row6 dn = load_row(i3, y0 + 1, x0);

    float sX2 = 0.f, sY2 = 0.f, sL1 = 0.f;

    #pragma unroll 1
    for (int k = 0; k < TH; ++k) {
        // consume prefetched row k+1 (arrived during previous iteration's compute)
        Row6 a2 = an, b2 = bn, c2 = cn, d2 = dn;

        // issue row k+2 now; consumed next iteration (>=1 compute phase in flight)
        const int yin = y0 + k + 2;
        an = load_row(i0, yin, x0);
        bn = load_row(i1, yin, x0);
        cn = load_row(i2, yin, x0);
        dn = load_row(i3, yin, x0);

        #pragma unroll
        for (int j = 0; j < 4; ++j) {
            float gv = sob(a0, a1, a2, j);
            float gi = sob(b0, b1, b2, j);
            float gX = sob(c0, c1, c2, j);
            float gY = sob(d0, d1, d2, j);
            sX2 += gX * gX;
            sY2 += gY * gY;
            sL1 += fabsf(gX - fmaxf(gv, gi));
        }

        a0 = a1; a1 = a2;
        b0 = b1; b1 = b2;
        c0 = c1; c1 = c2;
        d0 = d1; d1 = d2;
    }

    // wave reduce (64 lanes), then 3-wave LDS reduce
    #pragma unroll
    for (int off = 32; off > 0; off >>= 1) {
        sX2 += __shfl_down(sX2, off);
        sY2 += __shfl_down(sY2, off);
        sL1 += __shfl_down(sL1, off);
    }
    const int wave = tid >> 6;
    const int lane = tid & 63;
    if (lane == 0) { red[0][wave] = sX2; red[1][wave] = sY2; red[2][wave] = sL1; }
    __syncthreads();
    if (tid == 0) {
        part[0 * NBLOCKS + bid] = red[0][0] + red[0][1] + red[0][2];
        part[1 * NBLOCKS + bid] = red[1][0] + red[1][1] + red[1][2];
        part[2 * NBLOCKS + bid] = red[2][0] + red[2][1] + red[2][2];
    }
}

__global__ __launch_bounds__(1024) void reduce_finalize(
    const float* __restrict__ part, float* __restrict__ out)
{
    __shared__ float red[3][16];
    const int tid = threadIdx.x;

    float a = 0.f, b = 0.f, c = 0.f;
    for (int i = tid; i < NBLOCKS; i += 1024) {
        a += part[0 * NBLOCKS + i];
        b += part[1 * NBLOCKS + i];
        c += part[2 * NBLOCKS + i];
    }
    #pragma unroll
    for (int off = 32; off > 0; off >>= 1) {
        a += __shfl_down(a, off);
        b += __shfl_down(b, off);
        c += __shfl_down(c, off);
    }
    const int wave = tid >> 6;
    const int lane = tid & 63;
    if (lane == 0) { red[0][wave] = a; red[1][wave] = b; red[2][wave] = c; }
    __syncthreads();
    if (tid == 0) {
        float sa = 0.f, sb = 0.f, sc = 0.f;
        #pragma unroll
        for (int w = 0; w < 16; ++w) { sa += red[0][w]; sb += red[1][w]; sc += red[2][w]; }
        out[0] = sb / sa;                      // loss_in = sumY2 / sumX2
        out[1] = sc * (1.f / (float)NPIX);     // loss_grad = sumL1 / N
    }
}

extern "C" void kernel_launch(void* const* d_in, const int* in_sizes, int n_in,
                              void* d_out, int out_size, void* d_ws, size_t ws_size,
                              hipStream_t stream) {
    const float* vis = (const float*)d_in[0];
    const float* ir  = (const float*)d_in[1];
    const float* X   = (const float*)d_in[2];
    const float* Y   = (const float*)d_in[3];
    float* out = (float*)d_out;
    float* part = (float*)d_ws;   // 3 * NBLOCKS floats = 24 KB

    dim3 grid(NSTRIPS, BATCH);    // 128 x 16 = 2048 blocks
    sobel_loss_main<<<grid, TPB, 0, stream>>>(vis, ir, X, Y, part);
    reduce_finalize<<<1, 1024, 0, stream>>>(part, out);
}